// Round 9
// baseline (279.120 us; speedup 1.0000x reference)
//
#include <hip/hip_runtime.h>
#include <hip/hip_bf16.h>
#include <stdint.h>

// Problem constants
#define TLEN 4096
#define DMm  2048
#define DD   4096
#define DGg  512
#define BT   8192          // B*T
#define DW   16384         // D*W

typedef __attribute__((ext_vector_type(8))) short bf16x8;
typedef __attribute__((ext_vector_type(4))) float f32x4;

__device__ __forceinline__ unsigned short f2bf(float f) {
    union { float f; unsigned u; } c; c.f = f;
    unsigned u = c.u;
    unsigned r = (u + 0x7FFFu + ((u >> 16) & 1u)) >> 16;   // RNE
    return (unsigned short)r;
}

// ---------------- fused cast f32 -> bf16 for gen|w1|w2 (contiguous in ws) ----
#define NB1 (BT * DMm / 4)
#define NB2 (DGg * DMm / 4)
#define NB3 (DW * DGg / 4)
__global__ void cast_all_kernel(const float* __restrict__ g,
                                const float* __restrict__ w1,
                                const float* __restrict__ w2,
                                unsigned short* __restrict__ o) {
    int i = blockIdx.x * blockDim.x + threadIdx.x;
    if (i >= NB1 + NB2 + NB3) return;
    const float* src; int j = i;
    if (j < NB1) { src = g; }
    else if (j < NB1 + NB2) { src = w1; j -= NB1; }
    else { src = w2; j -= NB1 + NB2; }
    float4 v = reinterpret_cast<const float4*>(src)[j];
    ushort4 u;
    u.x = f2bf(v.x); u.y = f2bf(v.y); u.z = f2bf(v.z); u.w = f2bf(v.w);
    reinterpret_cast<ushort4*>(o)[i] = u;
}

#define GLDS16(gp, lp)                                                         \
    __builtin_amdgcn_global_load_lds(                                          \
        (__attribute__((address_space(1))) const void*)(gp),                   \
        (__attribute__((address_space(3))) void*)(lp), 16, 0, 0)

#define VMCNT(n) asm volatile("s_waitcnt vmcnt(" #n ")" ::: "memory")
#define SBAR()   __builtin_amdgcn_s_barrier()
#define SCHED0() __builtin_amdgcn_sched_barrier(0)

// ---------------- GEMM1: h = silu(gen @ w1^T), bf16 out (unchanged) ----------
__global__ __launch_bounds__(256) void gemm1_silu_kernel(
    const unsigned short* __restrict__ A,
    const unsigned short* __restrict__ Bm,
    unsigned short* __restrict__ H)
{
    __shared__ short smA[128 * 32];
    __shared__ short smB[128 * 32];
    const int m0   = blockIdx.y * 128;
    const int n0   = blockIdx.x * 128;
    const int lane = threadIdx.x & 63;
    const int wave = threadIdx.x >> 6;
    const int wm   = wave >> 1, wn = wave & 1;

    const int c0 = wave * 64 + lane;
    const int c1 = c0 + 256;
    const int rA0 = m0 + (c0 >> 2), rA1 = m0 + (c1 >> 2);
    const int rB0 = n0 + (c0 >> 2), rB1 = n0 + (c1 >> 2);
    const int ko0 = (c0 & 3) * 8,  ko1 = (c1 & 3) * 8;

    f32x4 acc[4][4] = {};

    for (int k0 = 0; k0 < DMm; k0 += 32) {
        GLDS16(A  + (size_t)rA0 * DMm + k0 + ko0, smA + wave * 512);
        GLDS16(A  + (size_t)rA1 * DMm + k0 + ko1, smA + 2048 + wave * 512);
        GLDS16(Bm + (size_t)rB0 * DMm + k0 + ko0, smB + wave * 512);
        GLDS16(Bm + (size_t)rB1 * DMm + k0 + ko1, smB + 2048 + wave * 512);
        __syncthreads();

        const int la = lane & 15, ko = (lane >> 4) * 8;
        bf16x8 af[4], bfr[4];
#pragma unroll
        for (int mm = 0; mm < 4; ++mm)
            af[mm] = *reinterpret_cast<const bf16x8*>(&smA[(wm * 64 + mm * 16 + la) * 32 + ko]);
#pragma unroll
        for (int nn = 0; nn < 4; ++nn)
            bfr[nn] = *reinterpret_cast<const bf16x8*>(&smB[(wn * 64 + nn * 16 + la) * 32 + ko]);
#pragma unroll
        for (int mm = 0; mm < 4; ++mm)
#pragma unroll
            for (int nn = 0; nn < 4; ++nn)
                acc[mm][nn] = __builtin_amdgcn_mfma_f32_16x16x32_bf16(
                    af[mm], bfr[nn], acc[mm][nn], 0, 0, 0);
        __syncthreads();
    }

#pragma unroll
    for (int mm = 0; mm < 4; ++mm) {
        int rowB = m0 + wm * 64 + mm * 16 + (lane >> 4) * 4;
#pragma unroll
        for (int nn = 0; nn < 4; ++nn) {
            int colG = n0 + wn * 64 + nn * 16 + (lane & 15);
#pragma unroll
            for (int j = 0; j < 4; ++j) {
                float v = acc[mm][nn][j];
                float s = v / (1.0f + __expf(-v));
                H[(size_t)(rowB + j) * DGg + colG] = f2bf(s);
            }
        }
    }
}

// ===== GEMM2 fused: 128n x 128t, 4 waves, ring-4 BK=32, 2 blocks/CU =====
// D[n][t] = sum_k W2b[n][k] * Hb[t][k]   (n = 4d+w; conv taps w = acc reg idx j)
// 4 waves (wm 0..1 x wn 0..1); wave 64n x 64t: aF[4] x bF[4] -> 16 MFMA,
// 8 ds_read_b128 per region + aF-prefetch (round-8 pattern).  LDS = 64 KB
// (A[4 par][128][64B] @0, B same @32768) -> 2 blocks/CU: each SIMD carries
// 2 waves from INDEPENDENT barrier domains, so one block's stall phases
// overlap the other's MFMA (m114 mechanism).
// Ledger (4 loads/thread/tile): prologue stages 0,1,2 (12) -> VMCNT(4)
// certifies {0,1}; region r (0..12) stages r+3, VMCNT(4) certifies r+2
// (in-flight = tile r+3's 4); r=13: VMCNT(0) certifies 15; 14,15 bare.
// vmcnt ALWAYS before the closing barrier (round-4 lesson).
// Epilogue overlay inside the 64K: X f32[131][44] @0, Y f32[128][44] @23056.
#define LDS_B2 32768
#define XSTR   44

__global__ __launch_bounds__(256, 2) void gemm2_conv_silu_kernel(
    const unsigned short* __restrict__ Hb,
    const unsigned short* __restrict__ W2b,
    const float* __restrict__ b2,
    const float* __restrict__ x,
    float* __restrict__ out)
{
    __shared__ __attribute__((aligned(16))) char lds[65536];
    const int tid  = threadIdx.x;
    const int lane = tid & 63, wave = tid >> 6;
    const int wm   = wave >> 1, wn = wave & 1;
    const int la   = lane & 15, hi = lane >> 4;

    // XCD-aware swizzle (8192 blocks, %8==0 -> bijective); t fast within XCD
    int bid = blockIdx.x;
    int swz = (bid & 7) * 1024 + (bid >> 3);
    const int n0 = (swz >> 6) * 128;   // 128 n-tiles
    const int t0 = (swz & 63) * 128;   // 64 t-tiles
    const int d0 = n0 >> 2;

    const int srow = lane >> 2;
    const int scol = ((lane & 3) ^ ((srow >> 1) & 3)) * 8;   // pre-swizzled src col

    auto stageA = [&](int tk, int p) {   // 2 loads/thread: 8KB tile (128 rows)
#pragma unroll
        for (int q = 0; q < 2; ++q) {
            int chunk = wave * 2 + q, row = chunk * 16 + srow;   // 0..127
            GLDS16(W2b + (size_t)(n0 + row) * DGg + tk * 32 + scol,
                   lds + p * 8192 + chunk * 1024);
        }
    };
    auto stageB = [&](int tk, int p) {   // 2 loads/thread: 8KB tile (128 rows)
#pragma unroll
        for (int q = 0; q < 2; ++q) {
            int chunk = wave * 2 + q, row = chunk * 16 + srow;
            GLDS16(Hb + (size_t)(t0 + row) * DGg + tk * 32 + scol,
                   lds + LDS_B2 + p * 8192 + chunk * 1024);
        }
    };

    f32x4 acc[4][4] = {};
    const int slotb = (hi ^ ((la >> 1) & 3)) * 16;   // swizzled 16B slot
    const int aOff  = (wm * 64 + la) * 64 + slotb;
    const int bOff  = LDS_B2 + (wn * 64 + la) * 64 + slotb;

    bf16x8 aFa[4], aFb[4];
    auto rdA = [&](bf16x8 (&dst)[4], int p) {
        const char* aB = lds + p * 8192 + aOff;
#pragma unroll
        for (int m = 0; m < 4; ++m)
            dst[m] = *reinterpret_cast<const bf16x8*>(aB + m * 1024);
    };

    auto body = [&](bf16x8 (&AC)[4], bf16x8 (&AN)[4], int pcur, int pnext,
                    int tkS, bool doStage, bool doPre) {
        bf16x8 bF[4];
        const char* bB = lds + pcur * 8192 + bOff;
#pragma unroll
        for (int nr = 0; nr < 4; ++nr)
            bF[nr] = *reinterpret_cast<const bf16x8*>(bB + nr * 1024);
        if (doPre) rdA(AN, pnext);
        if (doStage) { stageA(tkS, tkS & 3); stageB(tkS, tkS & 3); }
        SCHED0();   // pin reads+stage above the MFMA cluster
        __builtin_amdgcn_s_setprio(1);
#pragma unroll
        for (int m = 0; m < 4; ++m)
#pragma unroll
            for (int nr = 0; nr < 4; ++nr)
                acc[m][nr] = __builtin_amdgcn_mfma_f32_16x16x32_bf16(
                    AC[m], bF[nr], acc[m][nr], 0, 0, 0);
        __builtin_amdgcn_s_setprio(0);
        SCHED0();
    };

    // ---- prologue: stage tiles 0,1,2 ----
    stageA(0, 0); stageB(0, 0);
    stageA(1, 1); stageB(1, 1);
    stageA(2, 2); stageB(2, 2);
    VMCNT(4);     // tiles 0,1 certified for all waves after the barrier
    SBAR();
    rdA(aFa, 0);

    // ---- main loop: regions 0..12 stage tile r+3 ----
#pragma unroll
    for (int r = 0; r < 13; ++r) {
        if (r & 1) body(aFb, aFa, r & 3, (r + 1) & 3, r + 3, true, true);
        else       body(aFa, aFb, r & 3, (r + 1) & 3, r + 3, true, true);
        VMCNT(4);   // certify tile r+2; tile r+3 (4 loads) in flight
        SBAR();
    }
    body(aFb, aFa, 1, 2, 0, false, true);   // r=13 (reads p1, prefetch aF(14))
    VMCNT(0); SBAR();                        // tile 15 certified

    // x loads issued here: regions 14,15 MFMA hide their latency; no vmcnt
    // follows, compiler waits on first use of xv.
    float4 xv[5];
#pragma unroll
    for (int k = 0; k < 5; ++k) {
        int c = tid + k * 256;                   // < 1048 = 131 rows * 8 chunks
        float4 v = make_float4(0.f, 0.f, 0.f, 0.f);
        if (c < 1048) {
            int row = c >> 3, q = c & 7;
            int rg = t0 - 3 + row;
            if (rg >= 0 && (rg >> 12) == (t0 >> 12))   // zero across batch boundary
                v = *reinterpret_cast<const float4*>(&x[(size_t)rg * DD + d0 + q * 4]);
        }
        xv[k] = v;
    }

    body(aFa, aFb, 2, 3, 0, false, true);   // r=14 (prefetch aF(15))
    body(aFb, aFa, 3, 0, 0, false, false);  // r=15

    __syncthreads();   // all K-loop LDS reads done; overlay X/Y

    float* smX = reinterpret_cast<float*>(lds);
#pragma unroll
    for (int k = 0; k < 5; ++k) {
        int c = tid + k * 256;
        if (c < 1048) {
            int row = c >> 3, q = c & 7;
            *reinterpret_cast<float4*>(&smX[row * XSTR + q * 4]) = xv[k];
        }
    }
    __syncthreads();

    // ---- epilogue: bias + conv taps (reg idx j) + silu -> smY ----
    float4 bb[4];
#pragma unroll
    for (int m = 0; m < 4; ++m)
        bb[m] = *reinterpret_cast<const float4*>(&b2[n0 + wm * 64 + m * 16 + hi * 4]);

    float* smY = reinterpret_cast<float*>(lds + 23056);
#pragma unroll
    for (int nr = 0; nr < 4; ++nr) {
        int tl = wn * 64 + nr * 16 + la;
#pragma unroll
        for (int m = 0; m < 4; ++m) {
            int dl = wm * 16 + m * 4 + hi;
            float pv =
                  (acc[m][nr][0] + bb[m].x) * smX[(tl + 0) * XSTR + dl]
                + (acc[m][nr][1] + bb[m].y) * smX[(tl + 1) * XSTR + dl]
                + (acc[m][nr][2] + bb[m].z) * smX[(tl + 2) * XSTR + dl]
                + (acc[m][nr][3] + bb[m].w) * smX[(tl + 3) * XSTR + dl];
            smY[tl * XSTR + dl] = pv / (1.0f + __expf(-pv));
        }
    }
    __syncthreads();

    // ---- coalesced store: 128 rows x 32 f32 (128 B per row) ----
    for (int c = tid; c < 128 * 8; c += 256) {
        int row = c >> 3, q = c & 7;
        float4 v = *reinterpret_cast<const float4*>(&smY[row * XSTR + q * 4]);
        *reinterpret_cast<float4*>(&out[(size_t)(t0 + row) * DD + d0 + q * 4]) = v;
    }
}

extern "C" void kernel_launch(void* const* d_in, const int* in_sizes, int n_in,
                              void* d_out, int out_size, void* d_ws, size_t ws_size,
                              hipStream_t stream) {
    const float* x   = (const float*)d_in[0];
    const float* gen = (const float*)d_in[1];
    const float* w1  = (const float*)d_in[2];
    const float* w2  = (const float*)d_in[3];
    const float* b2  = (const float*)d_in[4];
    float* out = (float*)d_out;

    char* ws = (char*)d_ws;
    size_t off = 0;
    unsigned short* gen_b = (unsigned short*)(ws + off); off += (size_t)BT * DMm * 2;
    unsigned short* w1_b  = (unsigned short*)(ws + off); off += (size_t)DGg * DMm * 2;
    unsigned short* w2_b  = (unsigned short*)(ws + off); off += (size_t)DW * DGg * 2;
    unsigned short* h_b   = (unsigned short*)(ws + off); off += (size_t)BT * DGg * 2;

    int total4 = NB1 + NB2 + NB3;
    cast_all_kernel<<<(total4 + 255) / 256, 256, 0, stream>>>(gen, w1, w2, gen_b);

    gemm1_silu_kernel<<<dim3(DGg / 128, BT / 128), 256, 0, stream>>>(gen_b, w1_b, h_b);
    gemm2_conv_silu_kernel<<<8192, 256, 0, stream>>>(h_b, w2_b, b2, x, out);
}

// Round 10
// 262.556 us; speedup vs baseline: 1.0631x; 1.0631x over previous
//
#include <hip/hip_runtime.h>
#include <hip/hip_bf16.h>
#include <stdint.h>

// Problem constants
#define TLEN 4096
#define DMm  2048
#define DD   4096
#define DGg  512
#define BT   8192          // B*T
#define DW   16384         // D*W

typedef __attribute__((ext_vector_type(8))) short bf16x8;
typedef __attribute__((ext_vector_type(4))) float f32x4;

__device__ __forceinline__ unsigned short f2bf(float f) {
    union { float f; unsigned u; } c; c.f = f;
    unsigned u = c.u;
    unsigned r = (u + 0x7FFFu + ((u >> 16) & 1u)) >> 16;   // RNE
    return (unsigned short)r;
}

// ---------------- fused cast f32 -> bf16 for gen|w1|w2 (contiguous in ws) ----
#define NB1 (BT * DMm / 4)
#define NB2 (DGg * DMm / 4)
#define NB3 (DW * DGg / 4)
__global__ void cast_all_kernel(const float* __restrict__ g,
                                const float* __restrict__ w1,
                                const float* __restrict__ w2,
                                unsigned short* __restrict__ o) {
    int i = blockIdx.x * blockDim.x + threadIdx.x;
    if (i >= NB1 + NB2 + NB3) return;
    const float* src; int j = i;
    if (j < NB1) { src = g; }
    else if (j < NB1 + NB2) { src = w1; j -= NB1; }
    else { src = w2; j -= NB1 + NB2; }
    float4 v = reinterpret_cast<const float4*>(src)[j];
    ushort4 u;
    u.x = f2bf(v.x); u.y = f2bf(v.y); u.z = f2bf(v.z); u.w = f2bf(v.w);
    reinterpret_cast<ushort4*>(o)[i] = u;
}

#define GLDS16(gp, lp)                                                         \
    __builtin_amdgcn_global_load_lds(                                          \
        (__attribute__((address_space(1))) const void*)(gp),                   \
        (__attribute__((address_space(3))) void*)(lp), 16, 0, 0)

#define VMCNT(n) asm volatile("s_waitcnt vmcnt(" #n ")" ::: "memory")
#define LGKM0()  asm volatile("s_waitcnt lgkmcnt(0)" ::: "memory")
#define SBAR()   __builtin_amdgcn_s_barrier()
#define SCHED0() __builtin_amdgcn_sched_barrier(0)

// ---------------- GEMM1: h = silu(gen @ w1^T), bf16 out (unchanged) ----------
__global__ __launch_bounds__(256) void gemm1_silu_kernel(
    const unsigned short* __restrict__ A,
    const unsigned short* __restrict__ Bm,
    unsigned short* __restrict__ H)
{
    __shared__ short smA[128 * 32];
    __shared__ short smB[128 * 32];
    const int m0   = blockIdx.y * 128;
    const int n0   = blockIdx.x * 128;
    const int lane = threadIdx.x & 63;
    const int wave = threadIdx.x >> 6;
    const int wm   = wave >> 1, wn = wave & 1;

    const int c0 = wave * 64 + lane;
    const int c1 = c0 + 256;
    const int rA0 = m0 + (c0 >> 2), rA1 = m0 + (c1 >> 2);
    const int rB0 = n0 + (c0 >> 2), rB1 = n0 + (c1 >> 2);
    const int ko0 = (c0 & 3) * 8,  ko1 = (c1 & 3) * 8;

    f32x4 acc[4][4] = {};

    for (int k0 = 0; k0 < DMm; k0 += 32) {
        GLDS16(A  + (size_t)rA0 * DMm + k0 + ko0, smA + wave * 512);
        GLDS16(A  + (size_t)rA1 * DMm + k0 + ko1, smA + 2048 + wave * 512);
        GLDS16(Bm + (size_t)rB0 * DMm + k0 + ko0, smB + wave * 512);
        GLDS16(Bm + (size_t)rB1 * DMm + k0 + ko1, smB + 2048 + wave * 512);
        __syncthreads();

        const int la = lane & 15, ko = (lane >> 4) * 8;
        bf16x8 af[4], bfr[4];
#pragma unroll
        for (int mm = 0; mm < 4; ++mm)
            af[mm] = *reinterpret_cast<const bf16x8*>(&smA[(wm * 64 + mm * 16 + la) * 32 + ko]);
#pragma unroll
        for (int nn = 0; nn < 4; ++nn)
            bfr[nn] = *reinterpret_cast<const bf16x8*>(&smB[(wn * 64 + nn * 16 + la) * 32 + ko]);
#pragma unroll
        for (int mm = 0; mm < 4; ++mm)
#pragma unroll
            for (int nn = 0; nn < 4; ++nn)
                acc[mm][nn] = __builtin_amdgcn_mfma_f32_16x16x32_bf16(
                    af[mm], bfr[nn], acc[mm][nn], 0, 0, 0);
        __syncthreads();
    }

#pragma unroll
    for (int mm = 0; mm < 4; ++mm) {
        int rowB = m0 + wm * 64 + mm * 16 + (lane >> 4) * 4;
#pragma unroll
        for (int nn = 0; nn < 4; ++nn) {
            int colG = n0 + wn * 64 + nn * 16 + (lane & 15);
#pragma unroll
            for (int j = 0; j < 4; ++j) {
                float v = acc[mm][nn][j];
                float s = v / (1.0f + __expf(-v));
                H[(size_t)(rowB + j) * DGg + colG] = f2bf(s);
            }
        }
    }
}

// ===== GEMM2 fused: m201-style 8-phase schedule, 256n x 256t, BK=64 =====
// D[n][t] = sum_k W2b[n][k] * Hb[t][k]   (n = 4d+w; conv taps w = acc reg idx j)
// 8 waves (wm 0..1 x wn 0..3); wave 128n x 64t; acc[8][4] f32x4.
// K = 512 -> 8 K-tiles (BK=64) -> 4 iterations x 8 phases.
// Phase (kh,nh): reads aF[0..7] (nh==0 only, 8 ds) + bF pair (2 ds), stages
// ONE half-tile (2 gload_lds), then SBAR; lgkm0; setprio1; 16 MFMA; setprio0;
// SBAR.  Half j (tile j>>1, khalf j&1) is read at phases {2j,2j+1} and staged
// at phase 2j-6 (3 half-periods ahead = m201's "3 half-tiles in flight");
// slot's old occupant was last read at phase 2j-7 -> write strictly after its
// closing barrier.  vmcnt(4) ONLY at ph3 (certifies tile read in ph4-7) and
// ph7 (certifies next iteration's first tile); tail vmcnt(0) at i=3/ph3.
// LDS: A[par][kh][256 rows][64B] = 64K @0; B same @65536 (128K in loop);
// post-loop overlay X f32[259][68] @0, Y f32[256][68] @70448 (140080 peak).
#define LDS_B2 65536

__global__ __launch_bounds__(512, 2) void gemm2_conv_silu_kernel(
    const unsigned short* __restrict__ Hb,
    const unsigned short* __restrict__ W2b,
    const float* __restrict__ b2,
    const float* __restrict__ x,
    float* __restrict__ out)
{
    __shared__ __attribute__((aligned(16))) char lds[140080];
    const int tid  = threadIdx.x;
    const int lane = tid & 63, wave = tid >> 6;
    const int wm   = wave >> 2, wn = wave & 3;
    const int la   = lane & 15, hi = lane >> 4;

    // XCD-aware swizzle (2048 blocks, %8==0 -> bijective); t fast within XCD
    int bid = blockIdx.x;
    int swz = (bid & 7) * 256 + (bid >> 3);
    const int n0 = (swz >> 5) * 256;   // 64 n-tiles
    const int t0 = (swz & 31) * 256;   // 32 t-tiles
    const int d0 = n0 >> 2;

    const int srow = lane >> 2;                               // 0..15
    const int scol = ((lane & 3) ^ ((srow >> 1) & 3)) * 8;    // pre-swizzled src col

    // stage one half-tile (256 rows x 32 k) = 2 gload_lds per thread
    auto stageA = [&](int tk, int kh) {
#pragma unroll
        for (int q = 0; q < 2; ++q) {
            int chunk = wave * 2 + q, row = chunk * 16 + srow;   // 0..255
            GLDS16(W2b + (size_t)(n0 + row) * DGg + tk * 64 + kh * 32 + scol,
                   lds + (tk & 1) * 32768 + kh * 16384 + chunk * 1024);
        }
    };
    auto stageB = [&](int tk, int kh) {
#pragma unroll
        for (int q = 0; q < 2; ++q) {
            int chunk = wave * 2 + q, row = chunk * 16 + srow;
            GLDS16(Hb + (size_t)(t0 + row) * DGg + tk * 64 + kh * 32 + scol,
                   lds + LDS_B2 + (tk & 1) * 32768 + kh * 16384 + chunk * 1024);
        }
    };

    f32x4 acc[8][4] = {};
    const int slotb = (hi ^ ((la >> 1) & 3)) * 16;   // swizzled 16B slot
    bf16x8 aF[8];

    auto rdA8 = [&](int par, int kh) {
        const char* base = lds + par * 32768 + kh * 16384 + (wm * 128 + la) * 64 + slotb;
#pragma unroll
        for (int m = 0; m < 8; ++m)
            aF[m] = *reinterpret_cast<const bf16x8*>(base + m * 1024);
    };

    // phase with nh=0 (acc cols 0,1) — also refreshes aF
    auto phase0 = [&](int par, int kh, auto stage, bool v4, bool v0) {
        rdA8(par, kh);
        const char* bb = lds + LDS_B2 + par * 32768 + kh * 16384 + (wn * 64 + la) * 64 + slotb;
        bf16x8 b0 = *reinterpret_cast<const bf16x8*>(bb);
        bf16x8 b1 = *reinterpret_cast<const bf16x8*>(bb + 1024);
        stage();
        if (v4) VMCNT(4);
        if (v0) VMCNT(0);
        SBAR(); LGKM0(); SCHED0();
        __builtin_amdgcn_s_setprio(1);
#pragma unroll
        for (int m = 0; m < 8; ++m) {
            acc[m][0] = __builtin_amdgcn_mfma_f32_16x16x32_bf16(aF[m], b0, acc[m][0], 0, 0, 0);
            acc[m][1] = __builtin_amdgcn_mfma_f32_16x16x32_bf16(aF[m], b1, acc[m][1], 0, 0, 0);
        }
        __builtin_amdgcn_s_setprio(0);
        SBAR();
    };
    // phase with nh=1 (acc cols 2,3) — reuses aF
    auto phase1 = [&](int par, int kh, auto stage, bool v4, bool v0) {
        const char* bb = lds + LDS_B2 + par * 32768 + kh * 16384 + (wn * 64 + la) * 64 + slotb;
        bf16x8 b0 = *reinterpret_cast<const bf16x8*>(bb + 2048);
        bf16x8 b1 = *reinterpret_cast<const bf16x8*>(bb + 3072);
        stage();
        if (v4) VMCNT(4);
        if (v0) VMCNT(0);
        SBAR(); LGKM0(); SCHED0();
        __builtin_amdgcn_s_setprio(1);
#pragma unroll
        for (int m = 0; m < 8; ++m) {
            acc[m][2] = __builtin_amdgcn_mfma_f32_16x16x32_bf16(aF[m], b0, acc[m][2], 0, 0, 0);
            acc[m][3] = __builtin_amdgcn_mfma_f32_16x16x32_bf16(aF[m], b1, acc[m][3], 0, 0, 0);
        }
        __builtin_amdgcn_s_setprio(0);
        SBAR();
    };
    auto nostage = [&]() {};

    // ---- prologue: halves 0..2 of A and B (tiles 0 full + tile 1 kh0) ----
    stageA(0, 0); stageB(0, 0);
    stageA(0, 1); stageB(0, 1);
    stageA(1, 0); stageB(1, 0);
    VMCNT(4);   // tile 0 (both halves) certified for all waves after barrier
    SBAR();

    // ---- main loop: 4 iterations x 8 phases ----
#pragma unroll
    for (int i = 0; i < 4; ++i) {
        const int s2 = 2 * i + 2, s3 = 2 * i + 3;
        // ph0..ph3 read tile 2i (par0); ph4..ph7 read tile 2i+1 (par1)
        phase0(0, 0, [&]{ stageA(2 * i + 1, 1); }, false, false);            // ph0
        phase1(0, 0, [&]{ stageB(2 * i + 1, 1); }, false, false);            // ph1
        phase0(0, 1, [&]{ if (s2 < 8) stageA(s2, 0); }, false, false);       // ph2
        phase1(0, 1, [&]{ if (s2 < 8) stageB(s2, 0); }, i < 3, i == 3);      // ph3
        phase0(1, 0, [&]{ if (s2 < 8) stageA(s2, 1); }, false, false);       // ph4
        phase1(1, 0, [&]{ if (s2 < 8) stageB(s2, 1); }, false, false);       // ph5
        phase0(1, 1, [&]{ if (s3 < 8) stageA(s3, 0); }, false, false);       // ph6
        phase1(1, 1, [&]{ if (s3 < 8) stageB(s3, 0); }, i < 3, false);       // ph7
    }

    // ---- x loads (post-loop; ride in regs until overlay is safe) ----
    float4 xv[9];
#pragma unroll
    for (int k = 0; k < 9; ++k) {
        int c = tid + k * 512;                   // < 4144 = 259 rows * 16 chunks
        float4 v = make_float4(0.f, 0.f, 0.f, 0.f);
        if (c < 4144) {
            int row = c >> 4, q = c & 15;
            int rg = t0 - 3 + row;
            if (rg >= 0 && (rg >> 12) == (t0 >> 12))   // zero across batch boundary
                v = *reinterpret_cast<const float4*>(&x[(size_t)rg * DD + d0 + q * 4]);
        }
        xv[k] = v;
    }
    __syncthreads();   // all K-loop LDS reads done; overlay X/Y

    float* smX = reinterpret_cast<float*>(lds);
#pragma unroll
    for (int k = 0; k < 9; ++k) {
        int c = tid + k * 512;
        if (c < 4144) {
            int row = c >> 4, q = c & 15;
            *reinterpret_cast<float4*>(&smX[row * 68 + q * 4]) = xv[k];
        }
    }
    __syncthreads();

    // ---- epilogue: bias + conv taps (reg idx j) + silu -> smY ----
    float4 bb[8];
#pragma unroll
    for (int m = 0; m < 8; ++m)
        bb[m] = *reinterpret_cast<const float4*>(&b2[n0 + wm * 128 + m * 16 + hi * 4]);

    float* smY = reinterpret_cast<float*>(lds + 70448);
#pragma unroll
    for (int nr = 0; nr < 4; ++nr) {
        int tl = wn * 64 + nr * 16 + la;
#pragma unroll
        for (int m = 0; m < 8; ++m) {
            int dl = wm * 32 + m * 4 + hi;
            float pv =
                  (acc[m][nr][0] + bb[m].x) * smX[(tl + 0) * 68 + dl]
                + (acc[m][nr][1] + bb[m].y) * smX[(tl + 1) * 68 + dl]
                + (acc[m][nr][2] + bb[m].z) * smX[(tl + 2) * 68 + dl]
                + (acc[m][nr][3] + bb[m].w) * smX[(tl + 3) * 68 + dl];
            smY[tl * 68 + dl] = pv / (1.0f + __expf(-pv));
        }
    }
    __syncthreads();

    // ---- coalesced store: 256 rows x 64 f32 (256 B per row) ----
    for (int c = tid; c < 256 * 16; c += 512) {
        int row = c >> 4, q = c & 15;
        float4 v = *reinterpret_cast<const float4*>(&smY[row * 68 + q * 4]);
        *reinterpret_cast<float4*>(&out[(size_t)(t0 + row) * DD + d0 + q * 4]) = v;
    }
}

extern "C" void kernel_launch(void* const* d_in, const int* in_sizes, int n_in,
                              void* d_out, int out_size, void* d_ws, size_t ws_size,
                              hipStream_t stream) {
    const float* x   = (const float*)d_in[0];
    const float* gen = (const float*)d_in[1];
    const float* w1  = (const float*)d_in[2];
    const float* w2  = (const float*)d_in[3];
    const float* b2  = (const float*)d_in[4];
    float* out = (float*)d_out;

    char* ws = (char*)d_ws;
    size_t off = 0;
    unsigned short* gen_b = (unsigned short*)(ws + off); off += (size_t)BT * DMm * 2;
    unsigned short* w1_b  = (unsigned short*)(ws + off); off += (size_t)DGg * DMm * 2;
    unsigned short* w2_b  = (unsigned short*)(ws + off); off += (size_t)DW * DGg * 2;
    unsigned short* h_b   = (unsigned short*)(ws + off); off += (size_t)BT * DGg * 2;

    int total4 = NB1 + NB2 + NB3;
    cast_all_kernel<<<(total4 + 255) / 256, 256, 0, stream>>>(gen, w1, w2, gen_b);

    gemm1_silu_kernel<<<dim3(DGg / 128, BT / 128), 256, 0, stream>>>(gen_b, w1_b, h_b);
    gemm2_conv_silu_kernel<<<2048, 512, 0, stream>>>(h_b, w2_b, b2, x, out);
}